// Round 1
// 403.565 us; speedup vs baseline: 1.0583x; 1.0583x over previous
//
#include <hip/hip_runtime.h>
#include <math.h>

#define B_ 32
#define H_ 64
#define D_ 512
#define ROPE_ 64
#define HALF_ 32
#define NB_ 2048
#define BS_ 64
#define MB_ 64
#define SMAX_ 4096
#define IH_ 64
#define ID_ 128
#define TOPK_ 512
#define SEL_CAP_ 544
#define KB_ROWS_ 576
#define SCALE_ 0.044194173824159216f

typedef __bf16 bf16x8 __attribute__((ext_vector_type(8)));
typedef float f32x4 __attribute__((ext_vector_type(4)));

__device__ __forceinline__ unsigned short f2bf(float f) {
  unsigned u = __float_as_uint(f);
  u += 0x7FFFu + ((u >> 16) & 1u);
  return (unsigned short)(u >> 16);
}

// lgkmcnt-only barrier: keeps prefetch global loads (vmcnt) in flight across
// the barrier; drains only LDS writes so other waves see them (8-phase pattern).
#define BARSYNC()                                        \
  do {                                                   \
    asm volatile("s_waitcnt lgkmcnt(0)" ::: "memory");   \
    __builtin_amdgcn_s_barrier();                        \
  } while (0)

// ---- K1: RoPE(q) -> qrb (bf16) ; dyn_quant(q_idx) -> qqb (bf16 ints), qs -------
__global__ __launch_bounds__(64) void k_prep(
    const float* __restrict__ q, const float* __restrict__ cosb,
    const float* __restrict__ sinb, const float* __restrict__ q_idx,
    unsigned short* __restrict__ qrb, unsigned short* __restrict__ qqb,
    float* __restrict__ qs) {
  int r = blockIdx.x, t = threadIdx.x;
  if (r < B_ * H_) {
    const float* x = q + (size_t)r * D_;
    unsigned short* y = qrb + (size_t)r * D_;
    int b = r >> 6;
    unsigned pk[4];
    if (t < 56) {
      float4 v0 = ((const float4*)x)[t * 2];
      float4 v1 = ((const float4*)x)[t * 2 + 1];
      pk[0] = f2bf(v0.x) | ((unsigned)f2bf(v0.y) << 16);
      pk[1] = f2bf(v0.z) | ((unsigned)f2bf(v0.w) << 16);
      pk[2] = f2bf(v1.x) | ((unsigned)f2bf(v1.y) << 16);
      pk[3] = f2bf(v1.z) | ((unsigned)f2bf(v1.w) << 16);
      *(uint4*)(y + t * 8) = make_uint4(pk[0], pk[1], pk[2], pk[3]);
    } else {
      int p0 = (t - 56) * 4;
#pragma unroll
      for (int i = 0; i < 4; i++) {
        int p = p0 + i;
        float c = cosb[b * HALF_ + p], s = sinb[b * HALF_ + p];
        float xe = x[448 + 2 * p], xo = x[448 + 2 * p + 1];
        float re = xe * c - xo * s;
        float ro = xe * s + xo * c;
        pk[i] = f2bf(re) | ((unsigned)f2bf(ro) << 16);
      }
      *(uint4*)(y + 448 + 8 * (t - 56)) = make_uint4(pk[0], pk[1], pk[2], pk[3]);
    }
  } else {
    int rr = r - B_ * H_;
    const float* x = q_idx + (size_t)rr * ID_;
    float2 v = *(const float2*)(x + t * 2);
    float m = fmaxf(fabsf(v.x), fabsf(v.y));
#pragma unroll
    for (int off = 32; off; off >>= 1) m = fmaxf(m, __shfl_xor(m, off));
    float scale = fmaxf(m, 1e-12f) / 127.0f;
    if (scale < 1e-6f) scale = 1.0f;
    float q0 = fminf(fmaxf(rintf(v.x / scale), -128.0f), 127.0f);
    float q1 = fminf(fmaxf(rintf(v.y / scale), -128.0f), 127.0f);
    ((unsigned*)qqb)[rr * (ID_ / 2) + t] = f2bf(q0) | ((unsigned)f2bf(q1) << 16);
    if (t == 0) qs[rr] = scale;
  }
}

// ---- K2: iscore[b,s] via exact int8 dot in bf16 MFMA ---------------------------
__global__ __launch_bounds__(256) void k_iscore(
    const float* __restrict__ k_idx_cache, const unsigned short* __restrict__ qqb,
    const float* __restrict__ qs, const int* __restrict__ block_tables,
    const int* __restrict__ seq_lens, float* __restrict__ iscore) {
  int m = blockIdx.x, b = blockIdx.y;
  int t = threadIdx.x, lane = t & 63, w = t >> 6;
  int s_base = m * BS_;
  int seq = seq_lens[b];
  float* out = iscore + (size_t)b * SMAX_ + s_base;
  if (s_base >= seq) {
    if (t < 64) out[t] = -INFINITY;
    return;
  }
  __shared__ __align__(16) unsigned short kq[64 * 136];
  __shared__ __align__(16) unsigned short qql[64 * 136];
  __shared__ float ksc[64];
  int phys = block_tables[b * MB_ + m];
  const float* krows = k_idx_cache + (size_t)phys * BS_ * ID_;
  int half = lane & 31, hw = lane >> 5;
  float4 vv[8];
#pragma unroll
  for (int rr = 0; rr < 8; rr++)
    vv[rr] = *(const float4*)(krows + (w * 16 + rr * 2 + hw) * ID_ + half * 4);
#pragma unroll
  for (int rr = 0; rr < 8; rr++) {
    int s = w * 16 + rr * 2 + hw;
    float4 v = vv[rr];
    float mx = fmaxf(fmaxf(fabsf(v.x), fabsf(v.y)), fmaxf(fabsf(v.z), fabsf(v.w)));
#pragma unroll
    for (int off = 1; off < 32; off <<= 1) mx = fmaxf(mx, __shfl_xor(mx, off));
    float scale = fmaxf(mx, 1e-12f) / 127.0f;
    if (scale < 1e-6f) scale = 1.0f;
    float q0 = fminf(fmaxf(rintf(v.x / scale), -128.0f), 127.0f);
    float q1 = fminf(fmaxf(rintf(v.y / scale), -128.0f), 127.0f);
    float q2 = fminf(fmaxf(rintf(v.z / scale), -128.0f), 127.0f);
    float q3 = fminf(fmaxf(rintf(v.w / scale), -128.0f), 127.0f);
    unsigned p0 = (unsigned)f2bf(q0) | ((unsigned)f2bf(q1) << 16);
    unsigned p1 = (unsigned)f2bf(q2) | ((unsigned)f2bf(q3) << 16);
    *(uint2*)((unsigned*)kq + s * 68 + half * 2) = make_uint2(p0, p1);
    if (half == 0) ksc[s] = scale;
  }
  const int4* qg = (const int4*)(qqb + (size_t)b * IH_ * ID_);
  for (int i = t; i < 64 * 16; i += 256) {
    int row = i >> 4, c = i & 15;
    *(int4*)((char*)qql + row * 272 + c * 16) = qg[row * 16 + c];
  }
  __syncthreads();
  int quad = lane >> 4, lr = lane & 15;
  float facc[4] = {0.f, 0.f, 0.f, 0.f};
  const float* qsrow = qs + b * IH_;
#pragma unroll
  for (int ht = 0; ht < 4; ht++) {
    f32x4 acc = {0.f, 0.f, 0.f, 0.f};
#pragma unroll
    for (int ks = 0; ks < 4; ks++) {
      bf16x8 a = *(const bf16x8*)(kq + (w * 16 + lr) * 136 + ks * 32 + quad * 8);
      bf16x8 bb = *(const bf16x8*)(qql + (ht * 16 + lr) * 136 + ks * 32 + quad * 8);
      acc = __builtin_amdgcn_mfma_f32_16x16x32_bf16(a, bb, acc, 0, 0, 0);
    }
    float qsv = qsrow[ht * 16 + lr];
#pragma unroll
    for (int r = 0; r < 4; r++) facc[r] += acc[r] * qsv;
  }
#pragma unroll
  for (int off = 1; off < 16; off <<= 1) {
#pragma unroll
    for (int r = 0; r < 4; r++) facc[r] += __shfl_xor(facc[r], off);
  }
  if (lr == 0) {
#pragma unroll
    for (int r = 0; r < 4; r++) {
      int sl = w * 16 + quad * 4 + r;
      out[sl] = (s_base + sl < seq) ? facc[r] * ksc[sl] : -INFINITY;
    }
  }
}

// ---- K3: exact top-512 radix select, wave-scan version -------------------------
__global__ __launch_bounds__(256) void k_topk(
    const float* __restrict__ iscore, int* __restrict__ keep_idx,
    int* __restrict__ keep_cnt) {
  int b = blockIdx.x, t = threadIdx.x;
  int lane = t & 63, w = t >> 6;
  __shared__ unsigned keys[SMAX_];
  __shared__ unsigned hist[4][256];
  __shared__ unsigned wtot[4];
  __shared__ unsigned sh_prefix, sh_remaining, sh_cnt;
  const float* row = iscore + (size_t)b * SMAX_;
  for (int i = t; i < SMAX_; i += 256) {
    unsigned u = __float_as_uint(row[i]);
    keys[i] = (u & 0x80000000u) ? ~u : (u | 0x80000000u);
  }
  if (t == 0) { sh_prefix = 0u; sh_remaining = TOPK_; sh_cnt = 0u; }
  hist[0][t] = 0u; hist[1][t] = 0u; hist[2][t] = 0u; hist[3][t] = 0u;
  __syncthreads();
  for (int pass = 0; pass < 4; pass++) {
    int shift = 24 - 8 * pass;
    unsigned prefix = sh_prefix;
    unsigned rem = sh_remaining;
    unsigned pmask = (pass == 0) ? 0u : (0xFFFFFFFFu << (shift + 8));
    for (int i = t; i < SMAX_; i += 256) {
      unsigned k = keys[i];
      if ((k & pmask) == prefix) atomicAdd(&hist[w][(k >> shift) & 255u], 1u);
    }
    __syncthreads();
    unsigned cnt_t = hist[0][t] + hist[1][t] + hist[2][t] + hist[3][t];
    hist[0][t] = 0u; hist[1][t] = 0u; hist[2][t] = 0u; hist[3][t] = 0u;
    unsigned v = cnt_t;
#pragma unroll
    for (int off = 1; off < 64; off <<= 1) {
      unsigned o = __shfl_down(v, off);
      if (lane + off < 64) v += o;
    }
    if (lane == 0) wtot[w] = v;
    __syncthreads();
    unsigned tail = 0;
    for (int w2 = w + 1; w2 < 4; w2++) tail += wtot[w2];
    unsigned S = v + tail;
    if (S >= rem && S - cnt_t < rem) {
      sh_prefix = prefix | ((unsigned)t << shift);
      sh_remaining = rem - (S - cnt_t);
    }
    __syncthreads();
  }
  unsigned K = sh_prefix, R = sh_remaining;
  int* kidx = keep_idx + b * SEL_CAP_;
  for (int i = t; i < SMAX_; i += 256) {
    if (keys[i] > K) {
      unsigned p = atomicAdd(&sh_cnt, 1u);
      kidx[p] = i;
    }
  }
  int lo = t * 16;
  unsigned ec = 0;
#pragma unroll
  for (int j = 0; j < 16; j++) ec += (keys[lo + j] == K) ? 1u : 0u;
  unsigned pv = ec;
#pragma unroll
  for (int off = 1; off < 64; off <<= 1) {
    unsigned o = __shfl_up(pv, off);
    if (lane >= off) pv += o;
  }
  if (lane == 63) wtot[w] = pv;
  __syncthreads();
  unsigned base_eq = 0;
  for (int w2 = 0; w2 < w; w2++) base_eq += wtot[w2];
  unsigned rank = base_eq + pv - ec;
  unsigned G = sh_cnt;
  for (int j = 0; j < 16; j++) {
    if (keys[lo + j] == K) {
      if (rank < R) kidx[G + rank] = lo + j;
      rank++;
    }
  }
  __syncthreads();
  bool kept0 = (keys[0] >= K);
  int cnt = kept0 ? TOPK_ : (TOPK_ + 1);
  if (t == 0) {
    if (!kept0) kidx[TOPK_] = 0;
    keep_cnt[b] = cnt;
  }
  for (int i = cnt + t; i < SEL_CAP_; i += 256) kidx[i] = 0;
}

// ---- K4: scores = qr.k * SCALE (+sink at s==0); also emit bf16 kv tiles --------
// 32-row tiles (grid 17x32 = 544 blocks, balanced), Q-frags in registers,
// double-buffered K-tile LDS, register-prefetch of next dr gather (T14).
__global__ __launch_bounds__(256) void k_scores(
    const float* __restrict__ kv_cache, const unsigned short* __restrict__ qrb,
    const float* __restrict__ attn_sink, const int* __restrict__ block_tables,
    const int* __restrict__ keep_idx, const int* __restrict__ keep_cnt,
    float* __restrict__ scores, unsigned short* __restrict__ kb16) {
  int c = blockIdx.x, b = blockIdx.y;
  int t = threadIdx.x, lane = t & 63, w = t >> 6;
  int cnt = keep_cnt[b];
  int base = c * 32;
  int n = min(cnt - base, 32);
  unsigned short* kbrow = kb16 + (size_t)(b * KB_ROWS_ + base) * D_;
  if (n <= 0) {
    // zero-fill kb16 rows [base, base+32) so K6 never multiplies 0 x poison
    for (int i = t; i < 32 * 32; i += 256) {
      int row = i >> 5, x = i & 31;
      *(uint4*)(kbrow + (size_t)row * D_ + x * 16) = make_uint4(0u, 0u, 0u, 0u);
    }
    return;
  }
  __shared__ __align__(16) unsigned short kt[2][32 * 136];
  __shared__ int srow_off[32];
  __shared__ int sglb[32];
  const int* kidx = keep_idx + b * SEL_CAP_;
  if (t < 32) {
    int sg = (t < n) ? kidx[base + t] : 0;
    sglb[t] = (t < n) ? sg : -1;
    srow_off[t] = block_tables[b * MB_ + (sg >> 6)] * BS_ + (sg & 63);
  }
  int quad = lane >> 4, lr = lane & 15;
  // Q fragments straight from global (L2-hot): [dr][ks], 16 x bf16x8
  bf16x8 qa[4][4];
  {
    const unsigned short* qrow = qrb + (size_t)(b * 64 + w * 16 + lr) * D_ + quad * 8;
#pragma unroll
    for (int dr = 0; dr < 4; dr++)
#pragma unroll
      for (int ks = 0; ks < 4; ks++)
        qa[dr][ks] = *(const bf16x8*)(qrow + dr * 128 + ks * 32);
  }
  __syncthreads();  // srow_off/sglb visible
  int prow = t >> 5, pd4 = t & 31;
  float4 pvA[4], pvB[4];
#pragma unroll
  for (int it = 0; it < 4; it++) {
    int row = prow + it * 8;
    pvA[it] = make_float4(0.f, 0.f, 0.f, 0.f);
    if (row < n)
      pvA[it] = *(const float4*)(kv_cache + (size_t)srow_off[row] * D_ + pd4 * 4);
  }
  f32x4 acc[2] = {};
#pragma unroll
  for (int dr = 0; dr < 4; dr++) {
    // issue next-dr gather early: latency hides under convert+write+bar+MFMA
    if (dr < 3) {
#pragma unroll
      for (int it = 0; it < 4; it++) {
        int row = prow + it * 8;
        pvB[it] = make_float4(0.f, 0.f, 0.f, 0.f);
        if (row < n)
          pvB[it] = *(const float4*)(kv_cache + (size_t)srow_off[row] * D_ +
                                     (dr + 1) * 128 + pd4 * 4);
      }
    }
    unsigned short* ktc = kt[dr & 1];
#pragma unroll
    for (int it = 0; it < 4; it++) {
      int row = prow + it * 8;
      float4 v = pvA[it];
      unsigned lo_ = f2bf(v.x) | ((unsigned)f2bf(v.y) << 16);
      unsigned hi_ = f2bf(v.z) | ((unsigned)f2bf(v.w) << 16);
      uint2 pk = make_uint2(lo_, hi_);
      *(uint2*)(ktc + row * 136 + pd4 * 4) = pk;
      *(uint2*)(kbrow + (size_t)row * D_ + dr * 128 + pd4 * 4) = pk;
    }
    BARSYNC();  // lgkm-only: pvB global loads stay in flight
#pragma unroll
    for (int ks = 0; ks < 4; ks++) {
#pragma unroll
      for (int st = 0; st < 2; st++) {
        bf16x8 bb = *(const bf16x8*)(ktc + (st * 16 + lr) * 136 + ks * 32 + quad * 8);
        acc[st] = __builtin_amdgcn_mfma_f32_16x16x32_bf16(qa[dr][ks], bb, acc[st], 0, 0, 0);
      }
    }
#pragma unroll
    for (int it = 0; it < 4; it++) pvA[it] = pvB[it];
    // no trailing barrier needed: double buffer + next iter's BARSYNC orders reuse
  }
#pragma unroll
  for (int st = 0; st < 2; st++) {
    int col = st * 16 + lr;
    if (col < n) {
      int sg = sglb[col];
#pragma unroll
      for (int r = 0; r < 4; r++) {
        int h = w * 16 + quad * 4 + r;
        float v = acc[st][r] * SCALE_;
        if (sg == 0) v += attn_sink[h];
        scores[((size_t)b * 64 + h) * SEL_CAP_ + base + col] = v;
      }
    }
  }
}

// ---- K5: softmax over kept, emit bf16 weights ----------------------------------
__global__ __launch_bounds__(64) void k_softmax(
    const int* __restrict__ keep_cnt, float* __restrict__ scores,
    unsigned short* __restrict__ wbf) {
  int r = blockIdx.x, t = threadIdx.x;
  int b = r >> 6;
  int cnt = keep_cnt[b];
  float* row = scores + (size_t)r * SEL_CAP_;
  float mx = -INFINITY;
  for (int i = t; i < cnt; i += 64) mx = fmaxf(mx, row[i]);
#pragma unroll
  for (int off = 32; off; off >>= 1) mx = fmaxf(mx, __shfl_xor(mx, off));
  float sum = 0.f;
  for (int i = t; i < cnt; i += 64) {
    float e = __expf(row[i] - mx);
    row[i] = e;
    sum += e;
  }
#pragma unroll
  for (int off = 32; off; off >>= 1) sum += __shfl_xor(sum, off);
  float inv = 1.0f / sum;
  unsigned short* wr = wbf + (size_t)r * SEL_CAP_;
  for (int i = t; i < SEL_CAP_; i += 64) {
    float v = (i < cnt) ? row[i] * inv : 0.f;
    wr[i] = f2bf(v);
  }
}

// ---- K6: out = w @ kb16 (bf16 MFMA, dbuf LDS transpose, reg prefetch) ----------
__global__ __launch_bounds__(256) void k_pv(
    const unsigned short* __restrict__ kb16, const unsigned short* __restrict__ wbf,
    float* __restrict__ out) {
  int dc = blockIdx.x, b = blockIdx.y;  // dc: 8 chunks of 64 d
  int t = threadIdx.x, lane = t & 63, w = t >> 6;
  __shared__ __align__(16) unsigned short ktr[2][64 * 72];  // [d][s], 36-int stride
  int quad = lane >> 4, lr = lane & 15;
  f32x4 acc[4] = {};
  const unsigned short* kbb = kb16 + (size_t)b * KB_ROWS_ * D_ + dc * 64;
  const unsigned short* wrow = wbf + (size_t)(b * 64 + w * 16 + lr) * SEL_CAP_;
  // all 17 A-operand fragments preloaded (SEL_CAP = 17*32); static-indexed
  bf16x8 wa[17];
#pragma unroll
  for (int j = 0; j < 17; j++) wa[j] = *(const bf16x8*)(wrow + j * 32 + quad * 8);
  int psg2 = t >> 4, pd4 = t & 15;
  ushort4 paA[2][2], paB[2][2];
#pragma unroll
  for (int it = 0; it < 2; it++) {
    int sg2 = psg2 + it * 16;
    int s0 = sg2 * 2;
    paA[it][0] = *(const ushort4*)(kbb + (size_t)s0 * D_ + pd4 * 4);
    paA[it][1] = *(const ushort4*)(kbb + (size_t)(s0 + 1) * D_ + pd4 * 4);
  }
#pragma unroll
  for (int sc = 0; sc < 9; sc++) {
    int width = (sc < 8) ? 64 : 32;
    if (sc < 8) {  // prefetch next tile into regs before touching LDS
      int nw = ((sc + 1) < 8) ? 64 : 32;
#pragma unroll
      for (int it = 0; it < 2; it++) {
        int sg2 = psg2 + it * 16;
        if (sg2 < (nw >> 1)) {
          int s0 = (sc + 1) * 64 + sg2 * 2;
          paB[it][0] = *(const ushort4*)(kbb + (size_t)s0 * D_ + pd4 * 4);
          paB[it][1] = *(const ushort4*)(kbb + (size_t)(s0 + 1) * D_ + pd4 * 4);
        }
      }
    }
    unsigned* kw = (unsigned*)ktr[sc & 1];
#pragma unroll
    for (int it = 0; it < 2; it++) {
      int sg2 = psg2 + it * 16;
      if (sg2 < (width >> 1)) {
        ushort4 a0 = paA[it][0], a1 = paA[it][1];
        kw[(pd4 * 4 + 0) * 36 + sg2] = (unsigned)a0.x | ((unsigned)a1.x << 16);
        kw[(pd4 * 4 + 1) * 36 + sg2] = (unsigned)a0.y | ((unsigned)a1.y << 16);
        kw[(pd4 * 4 + 2) * 36 + sg2] = (unsigned)a0.z | ((unsigned)a1.z << 16);
        kw[(pd4 * 4 + 3) * 36 + sg2] = (unsigned)a0.w | ((unsigned)a1.w << 16);
      }
    }
    BARSYNC();  // lgkm-only: paB loads stay in flight
    const unsigned short* ktc = ktr[sc & 1];
    int ksteps = width >> 5;
#pragma unroll
    for (int ks = 0; ks < 2; ks++) {
      if (ks < ksteps) {
        bf16x8 a = wa[sc * 2 + ks];
#pragma unroll
        for (int nt = 0; nt < 4; nt++) {
          bf16x8 bb = *(const bf16x8*)(ktc + (nt * 16 + lr) * 72 + ks * 32 + quad * 8);
          acc[nt] = __builtin_amdgcn_mfma_f32_16x16x32_bf16(a, bb, acc[nt], 0, 0, 0);
        }
      }
    }
#pragma unroll
    for (int it = 0; it < 2; it++) { paA[it][0] = paB[it][0]; paA[it][1] = paB[it][1]; }
  }
#pragma unroll
  for (int nt = 0; nt < 4; nt++) {
#pragma unroll
    for (int r = 0; r < 4; r++) {
      int h = w * 16 + quad * 4 + r;
      int d = dc * 64 + nt * 16 + lr;
      out[((size_t)b * 64 + h) * D_ + d] = acc[nt][r];
    }
  }
}

extern "C" void kernel_launch(void* const* d_in, const int* in_sizes, int n_in,
                              void* d_out, int out_size, void* d_ws, size_t ws_size,
                              hipStream_t stream) {
  (void)in_sizes; (void)n_in; (void)out_size; (void)ws_size;
  const float* q = (const float*)d_in[0];
  const float* cosb = (const float*)d_in[1];
  const float* sinb = (const float*)d_in[2];
  const float* kv_cache = (const float*)d_in[3];
  const float* q_idx = (const float*)d_in[4];
  const float* k_idx = (const float*)d_in[5];
  const float* sink = (const float*)d_in[6];
  const int* btab = (const int*)d_in[7];
  const int* slen = (const int*)d_in[8];
  float* out = (float*)d_out;
  char* ws = (char*)d_ws;
  unsigned short* qrb = (unsigned short*)(ws + 0);          // 2,097,152
  unsigned short* qqb = (unsigned short*)(ws + 2097152);    //   524,288
  float* qs = (float*)(ws + 2621440);                       //     8,192
  float* iscore = (float*)(ws + 2629632);                   //   524,288
  int* keep_idx = (int*)(ws + 3141632);                     //    69,632
  int* keep_cnt = (int*)(ws + 3211264);                     //     1,024 (padded)
  float* scores = (float*)(ws + 3212288);                   // 4,456,448
  unsigned short* wbf = (unsigned short*)(ws + 7668736);    // 2,228,224
  unsigned short* kb16 = (unsigned short*)(ws + 9896960);   // 18,874,368 (total ~28.8 MB)

  k_prep<<<dim3(4096), dim3(64), 0, stream>>>(q, cosb, sinb, q_idx, qrb, qqb, qs);
  k_iscore<<<dim3(64, 32), dim3(256), 0, stream>>>(k_idx, qqb, qs, btab, slen, iscore);
  k_topk<<<dim3(32), dim3(256), 0, stream>>>(iscore, keep_idx, keep_cnt);
  k_scores<<<dim3(17, 32), dim3(256), 0, stream>>>(kv_cache, qrb, sink, btab, keep_idx, keep_cnt, scores, kb16);
  k_softmax<<<dim3(2048), dim3(64), 0, stream>>>(keep_cnt, scores, wbf);
  k_pv<<<dim3(8, 32), dim3(256), 0, stream>>>(kb16, wbf, out);
}